// Round 1
// baseline (31.366 us; speedup 1.0000x reference)
//
#include <hip/hip_runtime.h>
#include <math.h>

#define NUM_CLASSES 1000
#define FEAT_DIM    512
#define BATCH       32768
#define LAMDA       0.5f
#define EPS         1e-8f

// ws layout (floats):
//   [0, 1000)                 inv_norm[j] = 1/max(||c_j||, EPS)
//   [1000, 2000)              diag[j]     = ||c_j||^2 * inv_norm[j]^2  (cos_jj)
//   [2048, 2048+50*512)       s partials  (50 blocks x 512)
//   [27648, 27648+4096)       center-loss partials (4096 blocks)
#define S_OFF   2048
#define CL_OFF  27648
#define CL_BLOCKS 4096
#define S_BLOCKS  50
#define ROWS_PER_SBLOCK 20   // 50*20 = 1000

__device__ inline float block_reduce(float v, float* sm) {
    // wave64 butterfly down-reduce
    for (int o = 32; o > 0; o >>= 1) v += __shfl_down(v, o, 64);
    const int wave = threadIdx.x >> 6, lane = threadIdx.x & 63;
    const int nwaves = (blockDim.x + 63) >> 6;
    if (lane == 0) sm[wave] = v;
    __syncthreads();
    if (wave == 0) {
        v = (lane < nwaves) ? sm[lane] : 0.f;
        for (int o = 4; o > 0; o >>= 1) v += __shfl_down(v, o, 64);
    }
    return v; // valid in thread 0 only
}

// 1000 blocks x 128 threads: per-center squared norm -> inv_norm, diag
__global__ void k_norms(const float* __restrict__ centers, float* __restrict__ ws) {
    const float4* c4 = (const float4*)centers;
    const int j = blockIdx.x;
    float4 c = c4[j * 128 + threadIdx.x];
    float v = c.x * c.x + c.y * c.y + c.z * c.z + c.w * c.w;
    for (int o = 32; o > 0; o >>= 1) v += __shfl_down(v, o, 64);
    __shared__ float sm[2];
    const int wave = threadIdx.x >> 6, lane = threadIdx.x & 63;
    if (lane == 0) sm[wave] = v;
    __syncthreads();
    if (threadIdx.x == 0) {
        const float n2  = sm[0] + sm[1];
        const float inv = 1.0f / fmaxf(sqrtf(n2), EPS);
        ws[j]        = inv;
        ws[1000 + j] = n2 * inv * inv;
    }
}

// 4096 blocks x 256 threads, grid-stride over float4 elements of feat
__global__ void k_center_loss(const float* __restrict__ feat,
                              const float* __restrict__ centers,
                              const int* __restrict__ label,
                              float* __restrict__ cl_part) {
    const float4* f4 = (const float4*)feat;
    const float4* c4 = (const float4*)centers;
    const int tid    = blockIdx.x * blockDim.x + threadIdx.x;
    const int stride = gridDim.x * blockDim.x;
    float acc = 0.f;
    const int total4 = BATCH * FEAT_DIM / 4; // 4194304
    for (int idx = tid; idx < total4; idx += stride) {
        const int sample = idx >> 7;   // 128 float4 per sample
        const int d4     = idx & 127;
        const int lbl    = label[sample];
        float4 f = f4[idx];
        float4 c = c4[lbl * 128 + d4];
        const float dx = f.x - c.x, dy = f.y - c.y, dz = f.z - c.z, dw = f.w - c.w;
        acc += dx * dx + dy * dy + dz * dz + dw * dw;
    }
    __shared__ float sm[4];
    const float total = block_reduce(acc, sm);
    if (threadIdx.x == 0) cl_part[blockIdx.x] = total;
}

// 50 blocks x 512 threads: partial weighted column sums of centers
__global__ void k_colsum(const float* __restrict__ centers,
                         const float* __restrict__ inv_norm,
                         float* __restrict__ s_part) {
    const int d  = threadIdx.x;        // 0..511
    const int b  = blockIdx.x;         // 0..49
    const int j0 = b * ROWS_PER_SBLOCK;
    float acc = 0.f;
#pragma unroll 4
    for (int j = j0; j < j0 + ROWS_PER_SBLOCK; ++j)
        acc += centers[j * FEAT_DIM + d] * inv_norm[j];
    s_part[b * FEAT_DIM + d] = acc;
}

// 1 block x 512 threads: combine everything
__global__ void k_final(const float* __restrict__ ws, float* __restrict__ out) {
    __shared__ float sm[8];
    const int t = threadIdx.x;

    // s[d] = sum of 50 partials, then dot(s,s)
    float s_d = 0.f;
#pragma unroll 10
    for (int b = 0; b < S_BLOCKS; ++b) s_d += ws[S_OFF + b * FEAT_DIM + t];
    const float dot = block_reduce(s_d * s_d, sm);
    __syncthreads();

    // diagonal (cos_jj) sum: 1000 entries
    float nsq_local = ws[1000 + t];
    if (t < 1000 - 512) nsq_local += ws[1000 + 512 + t];
    const float nsq = block_reduce(nsq_local, sm);
    __syncthreads();

    // center loss partial sum: 4096 entries
    float cl_local = 0.f;
#pragma unroll 8
    for (int b = t; b < CL_BLOCKS; b += 512) cl_local += ws[CL_OFF + b];
    const float cl = block_reduce(cl_local, sm);

    if (t == 0) {
        const float island = dot - nsq + (float)NUM_CLASSES * (float)(NUM_CLASSES - 1);
        out[0] = cl * 0.5f / (float)BATCH + LAMDA * island;
    }
}

extern "C" void kernel_launch(void* const* d_in, const int* in_sizes, int n_in,
                              void* d_out, int out_size, void* d_ws, size_t ws_size,
                              hipStream_t stream) {
    const int*   label   = (const int*)d_in[0];
    const float* feat    = (const float*)d_in[1];
    const float* centers = (const float*)d_in[2];
    float* ws  = (float*)d_ws;
    float* out = (float*)d_out;

    k_norms<<<NUM_CLASSES, 128, 0, stream>>>(centers, ws);
    k_center_loss<<<CL_BLOCKS, 256, 0, stream>>>(feat, centers, label, ws + CL_OFF);
    k_colsum<<<S_BLOCKS, 512, 0, stream>>>(centers, ws, ws + S_OFF);
    k_final<<<1, 512, 0, stream>>>(ws, out);
}

// Round 2
// 24.703 us; speedup vs baseline: 1.2697x; 1.2697x over previous
//
#include <hip/hip_runtime.h>
#include <math.h>

#define NUM_CLASSES 1000
#define FEAT_DIM    512
#define BATCH       32768
#define LAMDA       0.5f
#define EPS         1e-8f

// fused-kernel geometry
#define SB 50                 // centers-pass blocks (block-specialized, first 50)
#define ROWS_PER_BLOCK 20     // 50*20 = 1000 center rows
#define CB 2048               // center-loss blocks

// ws layout (floats):
//   [0, 50*512)        s partials (per centers-block weighted column sums)
#define DIAG_OFF 25600     // [25600, 25650) diag partials (per centers-block)
#define CL_OFF   26624     // [26624, 26624+2048) center-loss partials

__device__ inline float block_reduce(float v, float* sm) {
    for (int o = 32; o > 0; o >>= 1) v += __shfl_down(v, o, 64);
    const int wave = threadIdx.x >> 6, lane = threadIdx.x & 63;
    const int nwaves = (blockDim.x + 63) >> 6;
    if (lane == 0) sm[wave] = v;
    __syncthreads();
    if (wave == 0) {
        v = (lane < nwaves) ? sm[lane] : 0.f;
        for (int o = 4; o > 0; o >>= 1) v += __shfl_down(v, o, 64);
    }
    return v; // valid in thread 0 only
}

// Fused main kernel: blocks [0,SB) = centers pass, blocks [SB,SB+CB) = center loss
__global__ __launch_bounds__(256) void k_main(const float* __restrict__ feat,
                                              const float* __restrict__ centers,
                                              const int* __restrict__ label,
                                              float* __restrict__ ws) {
    if (blockIdx.x < SB) {
        // ---- centers pass: row norms -> inv, s += c*inv, diag += n2*inv^2 ----
        const float4* c4 = (const float4*)centers;
        const int w = threadIdx.x >> 6, l = threadIdx.x & 63;
        const int j0 = blockIdx.x * ROWS_PER_BLOCK;
        float4 sa = make_float4(0.f, 0.f, 0.f, 0.f);
        float4 sb = make_float4(0.f, 0.f, 0.f, 0.f);
        float diag = 0.f;
        for (int r = w; r < ROWS_PER_BLOCK; r += 4) {  // 5 rows per wave
            const int j = j0 + r;
            const float4 a = c4[j * 128 + l];
            const float4 b = c4[j * 128 + 64 + l];
            float n2 = a.x*a.x + a.y*a.y + a.z*a.z + a.w*a.w
                     + b.x*b.x + b.y*b.y + b.z*b.z + b.w*b.w;
            for (int o = 32; o > 0; o >>= 1) n2 += __shfl_xor(n2, o, 64);
            const float inv = 1.0f / fmaxf(sqrtf(n2), EPS);
            sa.x += a.x * inv; sa.y += a.y * inv; sa.z += a.z * inv; sa.w += a.w * inv;
            sb.x += b.x * inv; sb.y += b.y * inv; sb.z += b.z * inv; sb.w += b.w * inv;
            diag += n2 * inv * inv;   // identical in all lanes
        }
        __shared__ float s_sh[4][512];
        __shared__ float d_sh[4];
        s_sh[w][4*l+0] = sa.x; s_sh[w][4*l+1] = sa.y;
        s_sh[w][4*l+2] = sa.z; s_sh[w][4*l+3] = sa.w;
        s_sh[w][256+4*l+0] = sb.x; s_sh[w][256+4*l+1] = sb.y;
        s_sh[w][256+4*l+2] = sb.z; s_sh[w][256+4*l+3] = sb.w;
        if (l == 0) d_sh[w] = diag;
        __syncthreads();
        const int t = threadIdx.x;
        const float v0 = s_sh[0][t] + s_sh[1][t] + s_sh[2][t] + s_sh[3][t];
        const float v1 = s_sh[0][t+256] + s_sh[1][t+256] + s_sh[2][t+256] + s_sh[3][t+256];
        ws[blockIdx.x * 512 + t]       = v0;
        ws[blockIdx.x * 512 + 256 + t] = v1;
        if (t == 0)
            ws[DIAG_OFF + blockIdx.x] = d_sh[0] + d_sh[1] + d_sh[2] + d_sh[3];
    } else {
        // ---- center loss: grid-stride over float4 elements of feat ----
        const float4* f4 = (const float4*)feat;
        const float4* c4 = (const float4*)centers;
        const int b      = blockIdx.x - SB;
        const int tid    = b * 256 + threadIdx.x;
        const int stride = CB * 256;
        float acc = 0.f;
        const int total4 = BATCH * FEAT_DIM / 4;  // 4194304
        for (int idx = tid; idx < total4; idx += stride) {
            const int sample = idx >> 7;   // 128 float4 per sample
            const int d4     = idx & 127;
            const int lbl    = label[sample];
            const float4 f = f4[idx];
            const float4 c = c4[lbl * 128 + d4];
            const float dx = f.x - c.x, dy = f.y - c.y, dz = f.z - c.z, dw = f.w - c.w;
            acc += dx * dx + dy * dy + dz * dz + dw * dw;
        }
        __shared__ float sm[4];
        const float total = block_reduce(acc, sm);
        if (threadIdx.x == 0) ws[CL_OFF + b] = total;
    }
}

// 1 block x 512 threads: combine everything
__global__ void k_final(const float* __restrict__ ws, float* __restrict__ out) {
    __shared__ float sm[8];
    const int t = threadIdx.x;

    // s[d] = sum of SB partials, then ||s||^2
    float s_d = 0.f;
#pragma unroll 10
    for (int b = 0; b < SB; ++b) s_d += ws[b * FEAT_DIM + t];
    const float dot = block_reduce(s_d * s_d, sm);
    __syncthreads();

    // diagonal sum
    const float dg = (t < SB) ? ws[DIAG_OFF + t] : 0.f;
    const float diag = block_reduce(dg, sm);
    __syncthreads();

    // center loss partial sum
    float cl_l = 0.f;
#pragma unroll 4
    for (int b = t; b < CB; b += 512) cl_l += ws[CL_OFF + b];
    const float cl = block_reduce(cl_l, sm);

    if (t == 0) {
        const float island = dot - diag + (float)NUM_CLASSES * (float)(NUM_CLASSES - 1);
        out[0] = cl * 0.5f / (float)BATCH + LAMDA * island;
    }
}

extern "C" void kernel_launch(void* const* d_in, const int* in_sizes, int n_in,
                              void* d_out, int out_size, void* d_ws, size_t ws_size,
                              hipStream_t stream) {
    const int*   label   = (const int*)d_in[0];
    const float* feat    = (const float*)d_in[1];
    const float* centers = (const float*)d_in[2];
    float* ws  = (float*)d_ws;
    float* out = (float*)d_out;

    k_main<<<SB + CB, 256, 0, stream>>>(feat, centers, label, ws);
    k_final<<<1, 512, 0, stream>>>(ws, out);
}